// Round 7
// baseline (167.206 us; speedup 1.0000x reference)
//
#include <hip/hip_runtime.h>
#include <hip/hip_bf16.h>
#include <math.h>

// YOLO decode + hard NMS, exact equivalent of the JAX reference.
// R7: 5 dispatches (decode zeroes hist; hist recomputes scal per block —
// max/min reductions are order-independent hence bitwise exact; thresh stores
// scal + a precomputed chunk ladder). k_nms: register-resident selections
// (v_readlane pre-test, no LDS chains), lane-parallel suf prefetch, no
// in-kernel binary searches on the hot path. Exact fallback retained.

#define NCLS  80
#define MAXB  100
#define N0    6912     // 48*48*3
#define N1    27648    // 96*96*3
#define NTOT  145152
#define NTILE 2268     // 64-box tiles
#define NHB   567      // NTOT/256
#define NB    4096     // histogram bins (linear in score)
#define CAP   2048     // global candidate capacity
#define CAPL  2048     // nms LDS key capacity (fallback)
#define NEGF  -3.402823466e38f
#define POSF   3.402823466e38f

// ws layout (bytes), ~0.8 MB. Zero region HIST..BINC = 9*NB ints (by decode).
#define WS_CONF 0
#define WS_SCAL (NTOT * 4)
#define WS_PART (WS_SCAL + 16)
#define WS_HIST (WS_PART + NTILE * 16)       // 8 shards * NB ints
#define WS_BINC (WS_HIST + 8 * NB * 4)       // NB ints (contiguous after HIST)
#define WS_SUF  (WS_BINC + NB * 4)
#define WS_META (WS_SUF + (NB + 4) * 4)      // 16B-aligned
#define WS_CAND (WS_META + 16)

// Bin index; identical expression everywhere -> identical rounding.
__device__ __forceinline__ int binOf(float s, float Smax) {
    int b = (int)((s / Smax) * (float)NB);
    return b > (NB - 1) ? (NB - 1) : b;
}
__device__ __forceinline__ float rdlane(float v, int l) {
    return __uint_as_float(__builtin_amdgcn_readlane(__float_as_uint(v), l));
}
// Bitwise-identical bbox recompute (same expressions/order as reference decode).
__device__ __forceinline__ void decodeBox(int idx, const float* __restrict__ g0,
        const float* __restrict__ g1, const float* __restrict__ g2,
        const float* __restrict__ anch,
        float& x1, float& y1, float& x2, float& y2) {
    const float* g; int H, ar, j;
    if (idx < N0)           { g = g0; H = 48;  ar = 2; j = idx; }
    else if (idx < N0 + N1) { g = g1; H = 96;  ar = 1; j = idx - N0; }
    else                    { g = g2; H = 192; ar = 0; j = idx - N0 - N1; }
    const float* r = g + (size_t)j * 85;
    float tx = r[0], ty = r[1], tw = r[2], th = r[3];
    int cell = j / 3, a = j - cell * 3;
    int hh = cell / H, ww = cell - hh * H;   // W == H
    float xc = (tx + (float)ww) / (float)H;
    float yc = (ty + (float)hh) / (float)H;
    float bw = expf(tw) * anch[ar * 6 + a * 2];
    float bh = expf(th) * anch[ar * 6 + a * 2 + 1];
    x1 = xc - bw * 0.5f; y1 = yc - bh * 0.5f;
    x2 = xc + bw * 0.5f; y2 = yc + bh * 0.5f;
}

// One 256-thread block per 64-box tile: 4 lanes per box. Writes conf+partials.
// First 144 blocks also zero hist+binCtr (9*NB ints) — read only by later
// dispatches, so no race.
__global__ __launch_bounds__(256) void k_decode(
        const float* __restrict__ g0, const float* __restrict__ g1,
        const float* __restrict__ g2, float* __restrict__ conf,
        float* __restrict__ part, int* __restrict__ histAll) {
    __shared__ float sm[5440];                // 64 boxes * 85 ch
    __shared__ float red[16];
    const int tid = threadIdx.x;
    const int tile = blockIdx.x;
    if (tile < 144) histAll[tile * 256 + tid] = 0;
    const float* p; int ibase, lt;
    if (tile < 108)      { p = g0; ibase = 0;       lt = tile; }
    else if (tile < 540) { p = g1; ibase = N0;      lt = tile - 108; }
    else                 { p = g2; ibase = N0 + N1; lt = tile - 540; }
    const float4* src = (const float4*)(p + (size_t)lt * 5440);   // 16B-aligned
    for (int w = tid; w < 1360; w += 256) ((float4*)sm)[w] = src[w];
    __syncthreads();

    const int b = tid >> 2, pp = tid & 3;     // 4 lanes per box, same wave
    const float* row = sm + b * 85;
    float best = row[5 + pp * 20];
    #pragma unroll
    for (int k = 1; k < 20; k++) best = fmaxf(best, row[5 + pp * 20 + k]);
    best = fmaxf(best, __shfl_xor(best, 1));  // full-box max on all 4 lanes
    best = fmaxf(best, __shfl_xor(best, 2));
    float cmx = NEGF, cmn = POSF;
    if (pp == 0) {
        float obj = row[4];
        conf[ibase + lt * 64 + b] = obj;
        cmx = obj; cmn = obj;
    }
    // block reduce {max/min box-max, max/min conf} -> plain stores (NO atomics)
    float mpmax = best, mpmin = best;
    for (int off = 32; off; off >>= 1) {
        mpmax = fmaxf(mpmax, __shfl_down(mpmax, off));
        mpmin = fminf(mpmin, __shfl_down(mpmin, off));
        cmx   = fmaxf(cmx,   __shfl_down(cmx,   off));
        cmn   = fminf(cmn,   __shfl_down(cmn,   off));
    }
    const int lane = tid & 63, wid = tid >> 6;
    if (lane == 0) {
        red[wid * 4 + 0] = mpmax; red[wid * 4 + 1] = mpmin;
        red[wid * 4 + 2] = cmx;   red[wid * 4 + 3] = cmn;
    }
    __syncthreads();
    if (tid == 0) {
        float a0 = red[0], a1 = red[1], a2 = red[2], a3 = red[3];
        for (int w = 1; w < 4; w++) {
            a0 = fmaxf(a0, red[w * 4 + 0]); a1 = fminf(a1, red[w * 4 + 1]);
            a2 = fmaxf(a2, red[w * 4 + 2]); a3 = fminf(a3, red[w * 4 + 3]);
        }
        part[tile * 4 + 0] = a0; part[tile * 4 + 1] = a1;
        part[tile * 4 + 2] = a2; part[tile * 4 + 3] = a3;
    }
}

// Sharded histogram. Each block recomputes scal from part[] (max/min: any
// reduction order is bitwise identical).
__global__ __launch_bounds__(256) void k_hist(const float* __restrict__ conf,
                                              const float* __restrict__ part,
                                              int* __restrict__ hist) {
    __shared__ float red[16];
    const int tid = threadIdx.x, lane = tid & 63, wid = tid >> 6;
    float a0 = NEGF, a1 = POSF, a2 = NEGF, a3 = POSF;
    for (int b = tid; b < NTILE; b += 256) {
        float4 p4 = ((const float4*)part)[b];
        a0 = fmaxf(a0, p4.x); a1 = fminf(a1, p4.y);
        a2 = fmaxf(a2, p4.z); a3 = fminf(a3, p4.w);
    }
    for (int off = 32; off; off >>= 1) {
        a0 = fmaxf(a0, __shfl_down(a0, off)); a1 = fminf(a1, __shfl_down(a1, off));
        a2 = fmaxf(a2, __shfl_down(a2, off)); a3 = fminf(a3, __shfl_down(a3, off));
    }
    if (lane == 0) {
        red[wid * 4 + 0] = a0; red[wid * 4 + 1] = a1;
        red[wid * 4 + 2] = a2; red[wid * 4 + 3] = a3;
    }
    __syncthreads();
    float Mx = fmaxf(fmaxf(red[0], red[4]),  fmaxf(red[8],  red[12]));
    float Mn = fminf(fminf(red[1], red[5]),  fminf(red[9],  red[13]));
    float cx = fmaxf(fmaxf(red[2], red[6]),  fmaxf(red[10], red[14]));
    float cn = fminf(fminf(red[3], red[7]),  fminf(red[11], red[15]));
    float Smax = fmaxf(fmaxf(cx * Mx, cx * Mn), fmaxf(cn * Mx, cn * Mn));
    int i = blockIdx.x * 256 + tid;           // grid == NTOT/256 exactly
    float c = conf[i];
    float s = fmaxf(c * Mx, c * Mn);          // == max_j conf_i * maxprob_j
    if (s > 0.0f && Smax > 0.0f)              // 8-way sharded to spread lines
        atomicAdd(&hist[((blockIdx.x & 7) << 12) + binOf(s, Smax)], 1);
}

// Sums shards -> suffix counts -> suf (global+LDS); computes chunk-ladder
// thresholds into meta (parallel LDS binary searches); stores scal.
__global__ __launch_bounds__(1024) void k_thresh(
        const int* __restrict__ hist, const float* __restrict__ part,
        int* __restrict__ suf, int* __restrict__ meta, float* __restrict__ scal) {
    __shared__ int grp[1024];
    __shared__ int sufL[NB + 1];
    __shared__ float red[64];
    const int tid = threadIdx.x, lane = tid & 63, wid = tid >> 6;
    // scal from part (order-independent max/min)
    float a0 = NEGF, a1 = POSF, a2 = NEGF, a3 = POSF;
    for (int b = tid; b < NTILE; b += 1024) {
        float4 p4 = ((const float4*)part)[b];
        a0 = fmaxf(a0, p4.x); a1 = fminf(a1, p4.y);
        a2 = fmaxf(a2, p4.z); a3 = fminf(a3, p4.w);
    }
    for (int off = 32; off; off >>= 1) {
        a0 = fmaxf(a0, __shfl_down(a0, off)); a1 = fminf(a1, __shfl_down(a1, off));
        a2 = fmaxf(a2, __shfl_down(a2, off)); a3 = fminf(a3, __shfl_down(a3, off));
    }
    if (lane == 0) {
        red[wid * 4 + 0] = a0; red[wid * 4 + 1] = a1;
        red[wid * 4 + 2] = a2; red[wid * 4 + 3] = a3;
    }
    // shard sums
    int b0 = tid * 4;
    int h[4];
    #pragma unroll
    for (int q = 0; q < 4; q++) {
        int ss = 0;
        #pragma unroll
        for (int sh = 0; sh < 8; sh++) ss += hist[sh * NB + b0 + q];
        h[q] = ss;
    }
    grp[tid] = h[0] + h[1] + h[2] + h[3];
    __syncthreads();
    for (int d = 1; d < 1024; d <<= 1) {      // Hillis-Steele suffix scan
        int add = (tid + d < 1024) ? grp[tid + d] : 0;
        __syncthreads();
        grp[tid] += add;
        __syncthreads();
    }
    int gnext = (tid + 1 < 1024) ? grp[tid + 1] : 0;
    int v3 = gnext + h[3], v2 = v3 + h[2], v1 = v2 + h[1], v0 = v1 + h[0];
    sufL[b0] = v0; sufL[b0 + 1] = v1; sufL[b0 + 2] = v2; sufL[b0 + 3] = v3;
    suf[b0] = v0;  suf[b0 + 1] = v1;  suf[b0 + 2] = v2;  suf[b0 + 3] = v3;
    if (tid == 0) { sufL[NB] = 0; suf[NB] = 0; }
    __syncthreads();
    if (tid < 4) {                            // ladder: min l with suf[l] <= cap
        int cap = 256 << tid;                 // 256,512,1024,2048
        int L = 0, R = NB - 1, res = NB - 1;
        while (L <= R) {
            int m = (L + R) >> 1;
            if (sufL[m] <= cap) { res = m; R = m - 1; } else L = m + 1;
        }
        meta[tid == 3 ? 0 : tid + 1] = res;   // meta[0]=thr2048, [1..3]=256/512/1024
    }
    if (tid == 4) {                           // fold 16 wave partials -> scal
        float m0 = red[0], m1 = red[1], m2 = red[2], m3 = red[3];
        for (int w = 1; w < 16; w++) {
            m0 = fmaxf(m0, red[w * 4 + 0]); m1 = fminf(m1, red[w * 4 + 1]);
            m2 = fmaxf(m2, red[w * 4 + 2]); m3 = fminf(m3, red[w * 4 + 3]);
        }
        scal[0] = m0; scal[1] = m1; scal[2] = m2; scal[3] = m3;
    }
}

__global__ __launch_bounds__(256) void k_compact(
        const float* __restrict__ conf, const float* __restrict__ scal,
        const int* __restrict__ suf, const int* __restrict__ meta,
        int* __restrict__ binCtr, unsigned long long* __restrict__ cand) {
    int i = blockIdx.x * 256 + threadIdx.x;
    float Mx = scal[0], Mn = scal[1], cx = scal[2], cn = scal[3];
    float Smax = fmaxf(fmaxf(cx * Mx, cx * Mn), fmaxf(cn * Mx, cn * Mn));
    float c = conf[i];
    float s = fmaxf(c * Mx, c * Mn);
    int lo = meta[0];
    if (s > 0.0f && Smax > 0.0f) {
        int b = binOf(s, Smax);
        if (b >= lo) {
            // exact position: (#cands in higher bins) + rank within bin
            int pos = suf[b + 1] + atomicAdd(&binCtr[b], 1);
            if (pos < CAP)
                // key: score bits | ~idx (ties: smallest idx first in desc sort)
                cand[pos] = ((unsigned long long)__float_as_uint(s) << 32)
                          | (unsigned long long)(~(unsigned)i);
        }
    }
}

// Single wave. Ladder chunks (precomputed boundaries), register-resident
// selections, v_readlane pre-test/accept. Exact fallback for lower bins.
__global__ __launch_bounds__(64) void k_nms(
        const float* __restrict__ g0, const float* __restrict__ g1,
        const float* __restrict__ g2, const float* __restrict__ anch,
        const float* __restrict__ conf, const float* __restrict__ scal,
        const int* __restrict__ suf, const int* __restrict__ meta,
        const unsigned long long* __restrict__ cand, float* __restrict__ out) {
    __shared__ unsigned long long keys[CAPL]; // 16 KB
    __shared__ float selX1[MAXB], selY1[MAXB], selX2[MAXB], selY2[MAXB], selS[MAXB];
    __shared__ int selIdx[MAXB];
    __shared__ int sh_cnt;

    const int lane = threadIdx.x;
    float4 sc4 = *(const float4*)scal;
    const float Mx = sc4.x, Mn = sc4.y;
    const float Smax = fmaxf(fmaxf(sc4.z * Mx, sc4.z * Mn),
                             fmaxf(sc4.w * Mx, sc4.w * Mn));
    int4 mt = *(const int4*)meta;             // x=thr2048, y=thr256, z=thr512, w=thr1024
    // lane-parallel prefetch of suf at ladder points (one latency round)
    int ladMine = 0;
    if (lane == 1) ladMine = mt.y; else if (lane == 2) ladMine = mt.z;
    else if (lane == 3) ladMine = mt.w; else if (lane == 4) ladMine = mt.x;
    int sufMine = (lane >= 1 && lane <= 4) ? suf[ladMine] : 0;
    const int sufA1 = __builtin_amdgcn_readlane(sufMine, 1);
    const int sufA2 = __builtin_amdgcn_readlane(sufMine, 2);
    const int sufA3 = __builtin_amdgcn_readlane(sufMine, 3);
    const int sufA4 = __builtin_amdgcn_readlane(sufMine, 4);

    int nsel = 0;
    // selection s lives in lane s (set0) / lane s-64 (set1)
    float s0x1 = 0, s0y1 = 0, s0x2 = 0, s0y2 = 0, s0a = 0;
    float s1x1 = 0, s1y1 = 0, s1x2 = 0, s1y2 = 0, s1a = 0;

    auto sortDesc = [&](int cnt) {
        int n = 2; while (n < cnt) n <<= 1;
        for (int i = cnt + lane; i < n; i += 64) keys[i] = 0ULL;
        __syncthreads();
        for (int k = 2; k <= n; k <<= 1) {
            for (int j = k >> 1; j > 0; j >>= 1) {
                int half = n >> 1;
                for (int t = lane; t < half; t += 64) {
                    int i = ((t & ~(j - 1)) << 1) | (t & (j - 1));
                    int ixj = i | j;
                    unsigned long long ka = keys[i], kb = keys[ixj];
                    if ((ka < kb) == ((i & k) == 0)) { keys[i] = kb; keys[ixj] = ka; }
                }
                __syncthreads();              // 1-wave block: cheap
            }
        }
    };

    auto sweep = [&](int cnt) {
        for (int bpos = 0; bpos < cnt && nsel < MAXB; bpos += 64) {
            int t = bpos + lane;
            bool alive = (t < cnt);
            float x1 = 0, y1 = 0, x2 = 0, y2 = 0, area = 0, sc = 0;
            int idx = 0;
            if (alive) {
                unsigned long long key = keys[t];
                idx = (int)(~(unsigned)key);
                sc = __uint_as_float((unsigned)(key >> 32));
                decodeBox(idx, g0, g1, g2, anch, x1, y1, x2, y2);
                area = (x2 - x1) * (y2 - y1);
            }
            // pre-test vs existing selections: uniform loop, readlane broadcast
            for (int s2 = 0; s2 < nsel; s2++) {
                float wx1, wy1, wx2, wy2, wa;
                if (s2 < 64) {
                    wx1 = rdlane(s0x1, s2); wy1 = rdlane(s0y1, s2);
                    wx2 = rdlane(s0x2, s2); wy2 = rdlane(s0y2, s2);
                    wa  = rdlane(s0a,  s2);
                } else {
                    int q = s2 - 64;
                    wx1 = rdlane(s1x1, q); wy1 = rdlane(s1y1, q);
                    wx2 = rdlane(s1x2, q); wy2 = rdlane(s1y2, q);
                    wa  = rdlane(s1a,  q);
                }
                if (alive) {
                    float iw = fmaxf(fminf(x2, wx2) - fmaxf(x1, wx1), 0.f);
                    float ih = fmaxf(fminf(y2, wy2) - fmaxf(y1, wy1), 0.f);
                    float inter = iw * ih;
                    if (inter / (area + wa - inter) > 0.5f) alive = false;
                }
            }
            // serial accept: first alive = next selection
            while (nsel < MAXB) {
                unsigned long long bal = __ballot(alive);
                if (!bal) break;
                int w = __ffsll(bal) - 1;
                float wx1 = rdlane(x1, w), wy1 = rdlane(y1, w);
                float wx2 = rdlane(x2, w), wy2 = rdlane(y2, w);
                float wa  = rdlane(area, w);
                if (lane == w) {              // winner records output entry
                    selX1[nsel] = x1; selY1[nsel] = y1;
                    selX2[nsel] = x2; selY2[nsel] = y2;
                    selS[nsel] = sc; selIdx[nsel] = idx;
                }
                if (nsel < 64) {
                    if (lane == nsel) { s0x1 = wx1; s0y1 = wy1; s0x2 = wx2; s0y2 = wy2; s0a = wa; }
                } else {
                    if (lane == nsel - 64) { s1x1 = wx1; s1y1 = wy1; s1x2 = wx2; s1y2 = wy2; s1a = wa; }
                }
                if (alive) {                  // winner kills itself (IoU=1)
                    float iw = fmaxf(fminf(x2, wx2) - fmaxf(x1, wx1), 0.f);
                    float ih = fmaxf(fminf(y2, wy2) - fmaxf(y1, wy1), 0.f);
                    float inter = iw * ih;
                    if (inter / (area + wa - inter) > 0.5f) alive = false;
                }
                nsel++;
            }
        }
    };

    // ladder chunks: bin ranges [thr256,NB), [thr512,thr256), ... (exact: bins
    // are monotone in score; ties share a bin; in-chunk sort is exact)
    int bases[4] = { 0, sufA1, sufA2, sufA3 };
    int ends[4]  = { sufA1, sufA2, sufA3, sufA4 };
    #pragma unroll
    for (int c = 0; c < 4; c++) {
        if (nsel >= MAXB) break;
        int base = bases[c], cnt = ends[c] - base;
        if (cnt <= 0) continue;
        for (int i = lane; i < cnt; i += 64) keys[i] = cand[base + i];
        sortDesc(cnt);
        sweep(cnt);
    }
    // exact fallback below thr2048 (cold path)
    int hi = mt.x, sufHi = sufA4;
    while (nsel < MAXB && hi > 0) {
        int L = 0, R = hi - 1, res = hi - 1, resV = 0;
        while (L <= R) {
            int m = (L + R) >> 1;
            int v = suf[m];
            if (v - sufHi <= CAPL) { res = m; resV = v; R = m - 1; } else L = m + 1;
        }
        int l = res;
        if (lane == 0) sh_cnt = 0;
        __syncthreads();
        for (int i = lane; i < NTOT; i += 64) {
            float c = conf[i];
            float s = fmaxf(c * Mx, c * Mn);
            if (s > 0.0f && Smax > 0.0f) {
                int b = binOf(s, Smax);
                if (b >= l && b < hi) {
                    int pos = atomicAdd(&sh_cnt, 1);
                    if (pos < CAPL)
                        keys[pos] = ((unsigned long long)__float_as_uint(s) << 32)
                                  | (unsigned long long)(~(unsigned)i);
                }
            }
        }
        __syncthreads();
        int cnt = sh_cnt; if (cnt > CAPL) cnt = CAPL;
        if (cnt > 0) { sortDesc(cnt); sweep(cnt); }
        hi = l; sufHi = resV;
    }
    __syncthreads();

    // outputs: boxes[100*4] | scores[100] | classes[100] | num_valid (all fp32)
    for (int k = lane; k < MAXB; k += 64) {
        float b0 = 0.f, b1 = 0.f, b2 = 0.f, b3 = 0.f, sv = 0.f, cv = 0.f;
        if (k < nsel) {
            b0 = selX1[k]; b1 = selY1[k]; b2 = selX2[k]; b3 = selY2[k];
            sv = selS[k];
            int idx = selIdx[k];              // class argmax only for selected
            const float* g; int j;
            if (idx < N0)           { g = g0; j = idx; }
            else if (idx < N0 + N1) { g = g1; j = idx - N0; }
            else                    { g = g2; j = idx - N0 - N1; }
            const float* r = g + (size_t)j * 85 + 5;
            float v[NCLS];
            #pragma unroll                    // all 80 loads in flight, one wait
            for (int q = 0; q < NCLS; q++) v[q] = r[q];
            float best = v[0]; int c = 0;
            #pragma unroll
            for (int q = 1; q < NCLS; q++)
                if (v[q] > best) { best = v[q]; c = q; }   // strict > = first max
            cv = (float)c;
        }
        out[4 * k + 0] = b0; out[4 * k + 1] = b1;
        out[4 * k + 2] = b2; out[4 * k + 3] = b3;
        out[400 + k] = sv;
        out[500 + k] = cv;
    }
    if (lane == 0) out[600] = (float)nsel;
}

extern "C" void kernel_launch(void* const* d_in, const int* in_sizes, int n_in,
                              void* d_out, int out_size, void* d_ws, size_t ws_size,
                              hipStream_t stream) {
    const float* g0   = (const float*)d_in[0];
    const float* g1   = (const float*)d_in[1];
    const float* g2   = (const float*)d_in[2];
    const float* anch = (const float*)d_in[3];
    char* ws = (char*)d_ws;
    float* conf  = (float*)(ws + WS_CONF);
    float* scal  = (float*)(ws + WS_SCAL);
    float* part  = (float*)(ws + WS_PART);
    int*   hist  = (int*)(ws + WS_HIST);
    int*   binc  = (int*)(ws + WS_BINC);
    int*   suf   = (int*)(ws + WS_SUF);
    int*   meta  = (int*)(ws + WS_META);
    unsigned long long* cand = (unsigned long long*)(ws + WS_CAND);
    float* out   = (float*)d_out;

    k_decode <<<NTILE, 256, 0, stream>>>(g0, g1, g2, conf, part, hist);
    k_hist   <<<NHB, 256, 0, stream>>>(conf, part, hist);
    k_thresh <<<1, 1024, 0, stream>>>(hist, part, suf, meta, scal);
    k_compact<<<NHB, 256, 0, stream>>>(conf, scal, suf, meta, binc, cand);
    k_nms    <<<1, 64, 0, stream>>>(g0, g1, g2, anch, conf, scal, suf, meta, cand, out);
}

// Round 8
// 164.410 us; speedup vs baseline: 1.0170x; 1.0170x over previous
//
#include <hip/hip_runtime.h>
#include <hip/hip_bf16.h>
#include <math.h>

// YOLO decode + hard NMS, exact equivalent of the JAX reference.
// R8: k_nms rewritten for code-size (single-wave kernels are I-fetch bound):
// ONE copy of gather/sort/decode/sweep; inverted sweep (lane s holds selection
// s in registers, candidate broadcast via uniform LDS reads — no bpermute, no
// per-accept LDS traffic). Ladder chunks + exact cold fallback unified.

#define NCLS  80
#define MAXB  100
#define N0    6912     // 48*48*3
#define N1    27648    // 96*96*3
#define NTOT  145152
#define NTILE 2268     // 64-box tiles
#define NHB   567      // NTOT/256
#define NB    4096     // histogram bins (linear in score)
#define CAP   2048     // global candidate capacity
#define CAPL  2048     // nms LDS key capacity (fallback)
#define NEGF  -3.402823466e38f
#define POSF   3.402823466e38f

// ws layout (bytes), ~0.8 MB. Zero region HIST..BINC = 9*NB ints (by decode).
#define WS_CONF 0
#define WS_SCAL (NTOT * 4)
#define WS_PART (WS_SCAL + 16)
#define WS_HIST (WS_PART + NTILE * 16)       // 8 shards * NB ints
#define WS_BINC (WS_HIST + 8 * NB * 4)       // NB ints (contiguous after HIST)
#define WS_SUF  (WS_BINC + NB * 4)
#define WS_META (WS_SUF + (NB + 4) * 4)      // 16B-aligned
#define WS_CAND (WS_META + 16)

// Bin index; identical expression everywhere -> identical rounding.
__device__ __forceinline__ int binOf(float s, float Smax) {
    int b = (int)((s / Smax) * (float)NB);
    return b > (NB - 1) ? (NB - 1) : b;
}
// Bitwise-identical bbox recompute (same expressions/order as reference decode).
__device__ __forceinline__ void decodeBox(int idx, const float* __restrict__ g0,
        const float* __restrict__ g1, const float* __restrict__ g2,
        const float* __restrict__ anch,
        float& x1, float& y1, float& x2, float& y2) {
    const float* g; int H, ar, j;
    if (idx < N0)           { g = g0; H = 48;  ar = 2; j = idx; }
    else if (idx < N0 + N1) { g = g1; H = 96;  ar = 1; j = idx - N0; }
    else                    { g = g2; H = 192; ar = 0; j = idx - N0 - N1; }
    const float* r = g + (size_t)j * 85;
    float tx = r[0], ty = r[1], tw = r[2], th = r[3];
    int cell = j / 3, a = j - cell * 3;
    int hh = cell / H, ww = cell - hh * H;   // W == H
    float xc = (tx + (float)ww) / (float)H;
    float yc = (ty + (float)hh) / (float)H;
    float bw = expf(tw) * anch[ar * 6 + a * 2];
    float bh = expf(th) * anch[ar * 6 + a * 2 + 1];
    x1 = xc - bw * 0.5f; y1 = yc - bh * 0.5f;
    x2 = xc + bw * 0.5f; y2 = yc + bh * 0.5f;
}

// One 256-thread block per 64-box tile: 4 lanes per box. Writes conf+partials.
// First 144 blocks also zero hist+binCtr (9*NB ints).
__global__ __launch_bounds__(256) void k_decode(
        const float* __restrict__ g0, const float* __restrict__ g1,
        const float* __restrict__ g2, float* __restrict__ conf,
        float* __restrict__ part, int* __restrict__ histAll) {
    __shared__ float sm[5440];                // 64 boxes * 85 ch
    __shared__ float red[16];
    const int tid = threadIdx.x;
    const int tile = blockIdx.x;
    if (tile < 144) histAll[tile * 256 + tid] = 0;
    const float* p; int ibase, lt;
    if (tile < 108)      { p = g0; ibase = 0;       lt = tile; }
    else if (tile < 540) { p = g1; ibase = N0;      lt = tile - 108; }
    else                 { p = g2; ibase = N0 + N1; lt = tile - 540; }
    const float4* src = (const float4*)(p + (size_t)lt * 5440);   // 16B-aligned
    for (int w = tid; w < 1360; w += 256) ((float4*)sm)[w] = src[w];
    __syncthreads();

    const int b = tid >> 2, pp = tid & 3;     // 4 lanes per box, same wave
    const float* row = sm + b * 85;
    float best = row[5 + pp * 20];
    #pragma unroll
    for (int k = 1; k < 20; k++) best = fmaxf(best, row[5 + pp * 20 + k]);
    best = fmaxf(best, __shfl_xor(best, 1));  // full-box max on all 4 lanes
    best = fmaxf(best, __shfl_xor(best, 2));
    float cmx = NEGF, cmn = POSF;
    if (pp == 0) {
        float obj = row[4];
        conf[ibase + lt * 64 + b] = obj;
        cmx = obj; cmn = obj;
    }
    float mpmax = best, mpmin = best;
    for (int off = 32; off; off >>= 1) {
        mpmax = fmaxf(mpmax, __shfl_down(mpmax, off));
        mpmin = fminf(mpmin, __shfl_down(mpmin, off));
        cmx   = fmaxf(cmx,   __shfl_down(cmx,   off));
        cmn   = fminf(cmn,   __shfl_down(cmn,   off));
    }
    const int lane = tid & 63, wid = tid >> 6;
    if (lane == 0) {
        red[wid * 4 + 0] = mpmax; red[wid * 4 + 1] = mpmin;
        red[wid * 4 + 2] = cmx;   red[wid * 4 + 3] = cmn;
    }
    __syncthreads();
    if (tid == 0) {
        float a0 = red[0], a1 = red[1], a2 = red[2], a3 = red[3];
        for (int w = 1; w < 4; w++) {
            a0 = fmaxf(a0, red[w * 4 + 0]); a1 = fminf(a1, red[w * 4 + 1]);
            a2 = fmaxf(a2, red[w * 4 + 2]); a3 = fminf(a3, red[w * 4 + 3]);
        }
        part[tile * 4 + 0] = a0; part[tile * 4 + 1] = a1;
        part[tile * 4 + 2] = a2; part[tile * 4 + 3] = a3;
    }
}

// Sharded histogram. Each block recomputes scal from part[] (max/min: any
// reduction order is bitwise identical).
__global__ __launch_bounds__(256) void k_hist(const float* __restrict__ conf,
                                              const float* __restrict__ part,
                                              int* __restrict__ hist) {
    __shared__ float red[16];
    const int tid = threadIdx.x, lane = tid & 63, wid = tid >> 6;
    float a0 = NEGF, a1 = POSF, a2 = NEGF, a3 = POSF;
    for (int b = tid; b < NTILE; b += 256) {
        float4 p4 = ((const float4*)part)[b];
        a0 = fmaxf(a0, p4.x); a1 = fminf(a1, p4.y);
        a2 = fmaxf(a2, p4.z); a3 = fminf(a3, p4.w);
    }
    for (int off = 32; off; off >>= 1) {
        a0 = fmaxf(a0, __shfl_down(a0, off)); a1 = fminf(a1, __shfl_down(a1, off));
        a2 = fmaxf(a2, __shfl_down(a2, off)); a3 = fminf(a3, __shfl_down(a3, off));
    }
    if (lane == 0) {
        red[wid * 4 + 0] = a0; red[wid * 4 + 1] = a1;
        red[wid * 4 + 2] = a2; red[wid * 4 + 3] = a3;
    }
    __syncthreads();
    float Mx = fmaxf(fmaxf(red[0], red[4]),  fmaxf(red[8],  red[12]));
    float Mn = fminf(fminf(red[1], red[5]),  fminf(red[9],  red[13]));
    float cx = fmaxf(fmaxf(red[2], red[6]),  fmaxf(red[10], red[14]));
    float cn = fminf(fminf(red[3], red[7]),  fminf(red[11], red[15]));
    float Smax = fmaxf(fmaxf(cx * Mx, cx * Mn), fmaxf(cn * Mx, cn * Mn));
    int i = blockIdx.x * 256 + tid;           // grid == NTOT/256 exactly
    float c = conf[i];
    float s = fmaxf(c * Mx, c * Mn);          // == max_j conf_i * maxprob_j
    if (s > 0.0f && Smax > 0.0f)              // 8-way sharded to spread lines
        atomicAdd(&hist[((blockIdx.x & 7) << 12) + binOf(s, Smax)], 1);
}

// Sums shards -> suffix counts -> suf; chunk-ladder thresholds -> meta; scal.
__global__ __launch_bounds__(1024) void k_thresh(
        const int* __restrict__ hist, const float* __restrict__ part,
        int* __restrict__ suf, int* __restrict__ meta, float* __restrict__ scal) {
    __shared__ int grp[1024];
    __shared__ int sufL[NB + 1];
    __shared__ float red[64];
    const int tid = threadIdx.x, lane = tid & 63, wid = tid >> 6;
    float a0 = NEGF, a1 = POSF, a2 = NEGF, a3 = POSF;
    for (int b = tid; b < NTILE; b += 1024) {
        float4 p4 = ((const float4*)part)[b];
        a0 = fmaxf(a0, p4.x); a1 = fminf(a1, p4.y);
        a2 = fmaxf(a2, p4.z); a3 = fminf(a3, p4.w);
    }
    for (int off = 32; off; off >>= 1) {
        a0 = fmaxf(a0, __shfl_down(a0, off)); a1 = fminf(a1, __shfl_down(a1, off));
        a2 = fmaxf(a2, __shfl_down(a2, off)); a3 = fminf(a3, __shfl_down(a3, off));
    }
    if (lane == 0) {
        red[wid * 4 + 0] = a0; red[wid * 4 + 1] = a1;
        red[wid * 4 + 2] = a2; red[wid * 4 + 3] = a3;
    }
    int b0 = tid * 4;
    int h[4];
    #pragma unroll
    for (int q = 0; q < 4; q++) {
        int ss = 0;
        #pragma unroll
        for (int sh = 0; sh < 8; sh++) ss += hist[sh * NB + b0 + q];
        h[q] = ss;
    }
    grp[tid] = h[0] + h[1] + h[2] + h[3];
    __syncthreads();
    for (int d = 1; d < 1024; d <<= 1) {      // Hillis-Steele suffix scan
        int add = (tid + d < 1024) ? grp[tid + d] : 0;
        __syncthreads();
        grp[tid] += add;
        __syncthreads();
    }
    int gnext = (tid + 1 < 1024) ? grp[tid + 1] : 0;
    int v3 = gnext + h[3], v2 = v3 + h[2], v1 = v2 + h[1], v0 = v1 + h[0];
    sufL[b0] = v0; sufL[b0 + 1] = v1; sufL[b0 + 2] = v2; sufL[b0 + 3] = v3;
    suf[b0] = v0;  suf[b0 + 1] = v1;  suf[b0 + 2] = v2;  suf[b0 + 3] = v3;
    if (tid == 0) { sufL[NB] = 0; suf[NB] = 0; }
    __syncthreads();
    if (tid < 4) {                            // ladder: min l with suf[l] <= cap
        int cap = 256 << tid;                 // 256,512,1024,2048
        int L = 0, R = NB - 1, res = NB - 1;
        while (L <= R) {
            int m = (L + R) >> 1;
            if (sufL[m] <= cap) { res = m; R = m - 1; } else L = m + 1;
        }
        meta[tid == 3 ? 0 : tid + 1] = res;   // meta[0]=thr2048, [1..3]=256/512/1024
    }
    if (tid == 4) {                           // fold 16 wave partials -> scal
        float m0 = red[0], m1 = red[1], m2 = red[2], m3 = red[3];
        for (int w = 1; w < 16; w++) {
            m0 = fmaxf(m0, red[w * 4 + 0]); m1 = fminf(m1, red[w * 4 + 1]);
            m2 = fmaxf(m2, red[w * 4 + 2]); m3 = fminf(m3, red[w * 4 + 3]);
        }
        scal[0] = m0; scal[1] = m1; scal[2] = m2; scal[3] = m3;
    }
}

__global__ __launch_bounds__(256) void k_compact(
        const float* __restrict__ conf, const float* __restrict__ scal,
        const int* __restrict__ suf, const int* __restrict__ meta,
        int* __restrict__ binCtr, unsigned long long* __restrict__ cand) {
    int i = blockIdx.x * 256 + threadIdx.x;
    float Mx = scal[0], Mn = scal[1], cx = scal[2], cn = scal[3];
    float Smax = fmaxf(fmaxf(cx * Mx, cx * Mn), fmaxf(cn * Mx, cn * Mn));
    float c = conf[i];
    float s = fmaxf(c * Mx, c * Mn);
    int lo = meta[0];
    if (s > 0.0f && Smax > 0.0f) {
        int b = binOf(s, Smax);
        if (b >= lo) {
            int pos = suf[b + 1] + atomicAdd(&binCtr[b], 1);
            if (pos < CAP)
                // key: score bits | ~idx (ties: smallest idx first in desc sort)
                cand[pos] = ((unsigned long long)__float_as_uint(s) << 32)
                          | (unsigned long long)(~(unsigned)i);
        }
    }
}

// Single wave. ONE copy of gather/sort/decode/sweep. Selections in registers
// (lane s = selection s); candidates broadcast from LDS (uniform reads).
__global__ __launch_bounds__(64) void k_nms(
        const float* __restrict__ g0, const float* __restrict__ g1,
        const float* __restrict__ g2, const float* __restrict__ anch,
        const float* __restrict__ conf, const float* __restrict__ scal,
        const int* __restrict__ suf, const int* __restrict__ meta,
        const unsigned long long* __restrict__ cand, float* __restrict__ out) {
    __shared__ unsigned long long keys[CAPL]; // 16 KB
    __shared__ float4 bxs[CAPL];              // 32 KB
    __shared__ int lad[5];
    __shared__ int sh_cnt;

    const int lane = threadIdx.x;
    float4 sc4 = *(const float4*)scal;
    const float Mx = sc4.x, Mn = sc4.y;
    const float Smax = fmaxf(fmaxf(sc4.z * Mx, sc4.z * Mn),
                             fmaxf(sc4.w * Mx, sc4.w * Mn));
    int4 mt = *(const int4*)meta;             // x=thr2048, y=thr256, z=thr512, w=thr1024
    // lane-parallel prefetch of suf at ladder points (one latency round)
    int ladMine = 0;
    if (lane == 1) ladMine = mt.y; else if (lane == 2) ladMine = mt.z;
    else if (lane == 3) ladMine = mt.w; else if (lane == 4) ladMine = mt.x;
    int sufMine = (lane >= 1 && lane <= 4) ? suf[ladMine] : 0;
    if (lane <= 4) lad[lane] = (lane == 0) ? 0 : sufMine;
    __syncthreads();
    const int sufA4 = lad[4];

    int nsel = 0;
    // selection s lives in lane s (set0) / lane s-64 (set1)
    float s0x1 = 0, s0y1 = 0, s0x2 = 0, s0y2 = 0, s0a = 0, s0s = 0;
    float s1x1 = 0, s1y1 = 0, s1x2 = 0, s1y2 = 0, s1a = 0, s1s = 0;
    int s0i = 0, s1i = 0;

    int chunkIdx = 0;
    int hi = mt.x, sufHi = sufA4;             // fallback state (bins < thr2048)

    while (nsel < MAXB) {
        int cnt = 0;
        if (chunkIdx < 4) {                   // ladder chunk from cand[]
            int base = lad[chunkIdx], end = lad[chunkIdx + 1];
            cnt = end - base;
            for (int i = lane; i < cnt; i += 64) keys[i] = cand[base + i];
            chunkIdx++;
            if (cnt <= 0) continue;
        } else {                              // exact cold fallback gather
            if (hi <= 0) break;
            int L = 0, R = hi - 1, res = hi - 1, resV = 0;
            while (L <= R) {
                int m = (L + R) >> 1;
                int v = suf[m];
                if (v - sufHi <= CAPL) { res = m; resV = v; R = m - 1; } else L = m + 1;
            }
            int l = res;
            if (lane == 0) sh_cnt = 0;
            __syncthreads();
            #pragma clang loop unroll(disable)
            for (int i = lane; i < NTOT; i += 64) {
                float c = conf[i];
                float s = fmaxf(c * Mx, c * Mn);
                if (s > 0.0f && Smax > 0.0f) {
                    int b = binOf(s, Smax);
                    if (b >= l && b < hi) {
                        int pos = atomicAdd(&sh_cnt, 1);
                        if (pos < CAPL)
                            keys[pos] = ((unsigned long long)__float_as_uint(s) << 32)
                                      | (unsigned long long)(~(unsigned)i);
                    }
                }
            }
            __syncthreads();
            cnt = sh_cnt; if (cnt > CAPL) cnt = CAPL;
            hi = l; sufHi = resV;
            if (cnt <= 0) continue;
        }
        __syncthreads();
        // bitonic sort, descending (single copy)
        int n = 2; while (n < cnt) n <<= 1;
        for (int i = cnt + lane; i < n; i += 64) keys[i] = 0ULL;
        __syncthreads();
        for (int k = 2; k <= n; k <<= 1) {
            for (int j = k >> 1; j > 0; j >>= 1) {
                int half = n >> 1;
                for (int t = lane; t < half; t += 64) {
                    int i = ((t & ~(j - 1)) << 1) | (t & (j - 1));
                    int ixj = i | j;
                    unsigned long long ka = keys[i], kb = keys[ixj];
                    if ((ka < kb) == ((i & k) == 0)) { keys[i] = kb; keys[ixj] = ka; }
                }
                __syncthreads();              // 1-wave block: cheap
            }
        }
        // parallel box decode into LDS (matches sorted key order)
        for (int t = lane; t < cnt; t += 64) {
            int idx = (int)(~(unsigned)keys[t]);
            float x1, y1, x2, y2;
            decodeBox(idx, g0, g1, g2, anch, x1, y1, x2, y2);
            bxs[t] = make_float4(x1, y1, x2, y2);
        }
        __syncthreads();
        // serial inverted sweep: one candidate per iteration, broadcast reads;
        // each lane IoU-tests vs its own selection registers. No LDS writes.
        for (int c2 = 0; c2 < cnt && nsel < MAXB; c2++) {
            unsigned long long key = keys[c2];
            float4 cb = bxs[c2];
            float ca = (cb.z - cb.x) * (cb.w - cb.y);
            bool sup = false;
            if (lane < nsel) {
                float iw = fmaxf(fminf(cb.z, s0x2) - fmaxf(cb.x, s0x1), 0.f);
                float ih = fmaxf(fminf(cb.w, s0y2) - fmaxf(cb.y, s0y1), 0.f);
                float inter = iw * ih;
                sup = inter / (ca + s0a - inter) > 0.5f;
            }
            if (lane + 64 < nsel) {
                float iw = fmaxf(fminf(cb.z, s1x2) - fmaxf(cb.x, s1x1), 0.f);
                float ih = fmaxf(fminf(cb.w, s1y2) - fmaxf(cb.y, s1y1), 0.f);
                float inter = iw * ih;
                sup |= inter / (ca + s1a - inter) > 0.5f;
            }
            if (__ballot(sup) == 0ULL) {      // accept
                if (lane == nsel) {
                    s0x1 = cb.x; s0y1 = cb.y; s0x2 = cb.z; s0y2 = cb.w; s0a = ca;
                    s0s = __uint_as_float((unsigned)(key >> 32));
                    s0i = (int)(~(unsigned)key);
                } else if (lane == nsel - 64) {
                    s1x1 = cb.x; s1y1 = cb.y; s1x2 = cb.z; s1y2 = cb.w; s1a = ca;
                    s1s = __uint_as_float((unsigned)(key >> 32));
                    s1i = (int)(~(unsigned)key);
                }
                nsel++;
            }
        }
    }

    // outputs: boxes[100*4] | scores[100] | classes[100] | num_valid (all fp32)
    for (int set = 0; set < 2; set++) {
        int k = lane + (set << 6);
        bool valid = (k < nsel) && (k < MAXB);
        float ox1 = set ? s1x1 : s0x1, oy1 = set ? s1y1 : s0y1;
        float ox2 = set ? s1x2 : s0x2, oy2 = set ? s1y2 : s0y2;
        float osc = set ? s1s : s0s;
        int   oi  = set ? s1i : s0i;
        float cv = 0.f;
        if (valid) {                          // class argmax for selected only
            const float* g; int j;
            if (oi < N0)           { g = g0; j = oi; }
            else if (oi < N0 + N1) { g = g1; j = oi - N0; }
            else                   { g = g2; j = oi - N0 - N1; }
            const float* r = g + (size_t)j * 85 + 5;
            float best = NEGF; int c = 0;
            #pragma unroll 8
            for (int q = 0; q < NCLS; q++) {
                float v = r[q];
                if (v > best) { best = v; c = q; }   // strict > = first max
            }
            cv = (float)c;
        }
        if (k < MAXB) {
            out[4 * k + 0] = valid ? ox1 : 0.f;
            out[4 * k + 1] = valid ? oy1 : 0.f;
            out[4 * k + 2] = valid ? ox2 : 0.f;
            out[4 * k + 3] = valid ? oy2 : 0.f;
            out[400 + k] = valid ? osc : 0.f;
            out[500 + k] = cv;
        }
    }
    if (lane == 0) out[600] = (float)nsel;
}

extern "C" void kernel_launch(void* const* d_in, const int* in_sizes, int n_in,
                              void* d_out, int out_size, void* d_ws, size_t ws_size,
                              hipStream_t stream) {
    const float* g0   = (const float*)d_in[0];
    const float* g1   = (const float*)d_in[1];
    const float* g2   = (const float*)d_in[2];
    const float* anch = (const float*)d_in[3];
    char* ws = (char*)d_ws;
    float* conf  = (float*)(ws + WS_CONF);
    float* scal  = (float*)(ws + WS_SCAL);
    float* part  = (float*)(ws + WS_PART);
    int*   hist  = (int*)(ws + WS_HIST);
    int*   binc  = (int*)(ws + WS_BINC);
    int*   suf   = (int*)(ws + WS_SUF);
    int*   meta  = (int*)(ws + WS_META);
    unsigned long long* cand = (unsigned long long*)(ws + WS_CAND);
    float* out   = (float*)d_out;

    k_decode <<<NTILE, 256, 0, stream>>>(g0, g1, g2, conf, part, hist);
    k_hist   <<<NHB, 256, 0, stream>>>(conf, part, hist);
    k_thresh <<<1, 1024, 0, stream>>>(hist, part, suf, meta, scal);
    k_compact<<<NHB, 256, 0, stream>>>(conf, scal, suf, meta, binc, cand);
    k_nms    <<<1, 64, 0, stream>>>(g0, g1, g2, anch, conf, scal, suf, meta, cand, out);
}